// Round 6
// baseline (152.472 us; speedup 1.0000x reference)
//
#include <hip/hip_runtime.h>
#include <hip/hip_fp16.h>

// DCNv2 R6: readlane-free vector gather in k_fused.
//   lane = (px = lane&15, q = lane>>4). Each lane owns one pixel's params
//   (weights packed (w,w), 4 clamped corner byte-addrs) and gathers 8 channels
//   (dwordx4) per corner per k-chunk: 16 dwordx4 + 64 v_pk_fma_f16 + 4 LDS b128
//   writes per tap. S rows padded to 68 words -> conflict-free b128 r/w.
//   Phase C (MFMA) identical to validated R5. One barrier per tap, S dbuf.

typedef unsigned int u32;
typedef __attribute__((ext_vector_type(8))) _Float16 f16x8;
typedef __attribute__((ext_vector_type(4))) float f32x4;

union U16 { uint4 u; f16x8 h; };
union H2U { __half2 h2; u32 u; };

static __device__ __forceinline__ u32 pkh(float a, float b) {
    H2U c; c.h2 = __float22half2_rn(make_float2(a, b)); return c.u;
}
static __device__ __forceinline__ u32 pkw(float w) {
    __half h = __float2half_rn(w);
    H2U c; c.h2 = __half2(h, h); return c.u;
}
static __device__ __forceinline__ u32 hfma2u(u32 a, u32 w, u32 acc) {
    H2U x, y, z; x.u = a; y.u = w; z.u = acc;
    z.h2 = __hfma2(x.h2, y.h2, z.h2); return z.u;
}
static __device__ __forceinline__ u32 hmul2u(u32 a, u32 w) {
    H2U x, y; x.u = a; y.u = w;
    y.h2 = __hmul2(x.h2, y.h2); return y.u;
}

#define B_   16
#define HW_  4096
#define CU_  64          // 128 ch = 64 fp16-pair words

// ---------------- kernel 1: NCHW f32 -> NHWC fp16 ----------------
__global__ __launch_bounds__(256) void k_transpose(const float* __restrict__ x,
                                                   u32* __restrict__ xtu) {
    __shared__ float tile[32][129];
    int blk = blockIdx.x, t = threadIdx.x;
    int b = blk >> 7, hw0 = (blk & 127) << 5;
    int hwl = t & 31, cg = t >> 5;
    const float* src = x + (size_t)b * 128 * HW_ + hw0 + hwl;
#pragma unroll
    for (int i = 0; i < 16; ++i) { int c = cg + (i << 3); tile[hwl][c] = src[(size_t)c * HW_]; }
    __syncthreads();
    u32* dst = xtu + ((size_t)b * HW_ + hw0) * CU_;
    int u = t & 63, hq = t >> 6;
#pragma unroll
    for (int j = 0; j < 8; ++j) {
        int hw = (hq << 3) + j;
        dst[(size_t)hw * CU_ + u] = pkh(tile[hw][2 * u], tile[hw][2 * u + 1]);
    }
}

// ---------------- kernel 2: weight prep ----------------
__global__ __launch_bounds__(256) void k_prep(const float* __restrict__ weight,
                                              const float* __restrict__ off_w,
                                              u32* __restrict__ wtu,
                                              u32* __restrict__ woffu) {
    int idx = blockIdx.x * 256 + threadIdx.x;
    if (idx < 73728) {
        int o = idx / 576, r = idx % 576;
        int n = r / 64, cu = r % 64, c = cu * 2;
        float a = weight[((size_t)(o * 128 + c)) * 9 + n];
        float b = weight[((size_t)(o * 128 + c + 1)) * 9 + n];
        wtu[idx] = pkh(a, b);
    } else if (idx < 73728 + 18432) {
        int k = idx - 73728;
        int o = k / 576, r = k % 576;
        int tap = r / 64, cu = r % 64, c = cu * 2;
        u32 v = 0u;
        if (o < 27) {
            float a = off_w[((size_t)(o * 128 + c)) * 9 + tap];
            float b = off_w[((size_t)(o * 128 + c + 1)) * 9 + tap];
            v = pkh(a, b);
        }
        woffu[k] = v;
    }
}

// ---------------- kernel 3: offset/mask conv via MFMA ----------------
__global__ __launch_bounds__(256) void k_offconv(const u32* __restrict__ xtu,
                                                 const u32* __restrict__ woffu,
                                                 const float* __restrict__ off_b,
                                                 float* __restrict__ offout) {
    __shared__ __align__(16) u32 S[3][64][64];
    int blk = ((blockIdx.x & 7) << 7) + (blockIdx.x >> 3);   // XCD-chunked
    int t = threadIdx.x;
    int b = blk >> 6, ho = blk & 63;
    const u32* xb = xtu + (size_t)b * HW_ * CU_;
    const uint4 z4 = {0u, 0u, 0u, 0u};
#pragma unroll
    for (int i = 0; i < 12; ++i) {
        int li = t + (i << 8);
        int r = li >> 10, rem = li & 1023;
        int px = rem >> 4, ch = rem & 15;
        int yy = ho + r - 1;
        uint4 v = ((unsigned)yy < 64u) ? *(const uint4*)(xb + ((yy << 6) + px) * CU_ + (ch << 2)) : z4;
        *(uint4*)&S[r][px][(ch ^ (px & 7)) << 2] = v;
    }
    __syncthreads();
    int lane = t & 63, w = t >> 6, l15 = lane & 15, lhi = lane >> 4;
    int ob = w >> 1, pb0 = (w & 1) << 1;
    f32x4 acc[2];
    acc[0] = (f32x4){0.f, 0.f, 0.f, 0.f};
    acc[1] = (f32x4){0.f, 0.f, 0.f, 0.f};
#pragma unroll 1
    for (int tap = 0; tap < 9; ++tap) {
        int ky = tap / 3, kx = tap % 3;
        int yy = ho + ky - 1;
        if ((unsigned)yy >= 64u) continue;
        U16 af[4];
#pragma unroll
        for (int ks = 0; ks < 4; ++ks)
            af[ks].u = *(const uint4*)(woffu + (size_t)(ob * 16 + l15) * 576
                                       + tap * 64 + ks * 16 + lhi * 4);
#pragma unroll
        for (int pp = 0; pp < 2; ++pp) {
            int pr = ((pb0 + pp) << 4) + l15;
            int pxs = pr + kx - 1;
            bool v = (unsigned)pxs < 64u;
            int pxc = v ? pxs : 0;
#pragma unroll
            for (int ks = 0; ks < 4; ++ks) {
                U16 sf;
                sf.u = v ? *(const uint4*)&S[ky][pxc][((ks * 4 + lhi) ^ (pxc & 7)) << 2] : z4;
                acc[pp] = __builtin_amdgcn_mfma_f32_16x16x32_f16(af[ks].h, sf.h, acc[pp], 0, 0, 0);
            }
        }
    }
    float* dst = offout + (size_t)b * 27 * HW_ + (ho << 6);
#pragma unroll
    for (int pp = 0; pp < 2; ++pp)
#pragma unroll
        for (int r = 0; r < 4; ++r) {
            int o = ob * 16 + lhi * 4 + r;
            if (o < 27) {
                float s = acc[pp][r] + off_b[o];
                if (o >= 18) s = 1.f / (1.f + __expf(-s));
                dst[(size_t)o * HW_ + ((pb0 + pp) << 4) + l15] = s;
            }
        }
}

// ---------------- kernel 4: fused sample + MFMA, vector gather ----------------
__global__ __launch_bounds__(256, 4) void k_fused(const u32* __restrict__ xtu,
                                                  const float* __restrict__ offout,
                                                  const u32* __restrict__ wtu,
                                                  const float* __restrict__ bias,
                                                  float* __restrict__ out) {
    __shared__ __align__(16) u32 S[2][64][68];   // dbuf, 68-word rows
    int blk = ((blockIdx.x & 7) << 7) + (blockIdx.x >> 3);   // XCD-chunked
    int t = threadIdx.x;
    int b = blk >> 6, ho = blk & 63;
    int w = t >> 6, lane = t & 63, l15 = lane & 15, lhi = lane >> 4;
    int o0 = w * 32;
    int pxa = (w << 4) + l15;        // pixel this lane gathers & owns params for
    int colb = lhi << 4;             // byte offset of this lane's ch-chunk in a px row

    f32x4 acc[2][4];
#pragma unroll
    for (int ob = 0; ob < 2; ++ob)
#pragma unroll
        for (int pb = 0; pb < 4; ++pb) acc[ob][pb] = (f32x4){0.f, 0.f, 0.f, 0.f};

    const float* offb = offout + (size_t)b * 27 * HW_ + ho * 64 + pxa;
    const char* xbb = (const char*)(xtu + (size_t)b * HW_ * CU_);

#pragma unroll 1
    for (int n = 0; n < 9; ++n) {
        // --- preload W fragments for this tap ---
        uint4 wf[2][4];
#pragma unroll
        for (int ob = 0; ob < 2; ++ob)
#pragma unroll
            for (int ks = 0; ks < 4; ++ks)
                wf[ob][ks] = *(const uint4*)(wtu + (size_t)(o0 + ob * 16 + l15) * 576
                                             + n * 64 + ks * 16 + lhi * 4);
        // --- A: per-lane pixel params ---
        float dy = offb[(size_t)(2 * n) * HW_];
        float dx = offb[(size_t)(2 * n + 1) * HW_];
        float m  = offb[(size_t)(18 + n) * HW_];
        float ys = (float)(ho + n / 3 - 1) + dy;
        float xs = (float)(pxa + n % 3 - 1) + dx;
        float y0f = floorf(ys), x0f = floorf(xs);
        float fy = ys - y0f, fx = xs - x0f;
        int y0 = (int)y0f, x0 = (int)x0f;
        bool vy0 = (unsigned)y0 < 64u, vy1 = (unsigned)(y0 + 1) < 64u;
        bool vx0 = (unsigned)x0 < 64u, vx1 = (unsigned)(x0 + 1) < 64u;
        u32 w00 = pkw((vy0 && vx0) ? (1.f - fy) * (1.f - fx) * m : 0.f);
        u32 w01 = pkw((vy0 && vx1) ? (1.f - fy) * fx * m : 0.f);
        u32 w10 = pkw((vy1 && vx0) ? fy * (1.f - fx) * m : 0.f);
        u32 w11 = pkw((vy1 && vx1) ? fy * fx * m : 0.f);
        int y0c = min(max(y0, 0), 63), y1c = min(max(y0 + 1, 0), 63);
        int x0c = min(max(x0, 0), 63), x1c = min(max(x0 + 1, 0), 63);
        // byte addrs of this lane's 16B chunk in each corner's px row
        int a00 = (y0c << 14) + (x0c << 8) + colb;
        int a01 = (y0c << 14) + (x1c << 8) + colb;
        int a10 = (y1c << 14) + (x0c << 8) + colb;
        int a11 = (y1c << 14) + (x1c << 8) + colb;
        // --- B: vector gather + packed blend, 4 ch-chunks of 8 ch ---
        int buf = n & 1;
#pragma unroll
        for (int k = 0; k < 4; ++k) {
            uint4 v0 = *(const uint4*)(xbb + a00 + k * 64);
            uint4 v1 = *(const uint4*)(xbb + a01 + k * 64);
            uint4 v2 = *(const uint4*)(xbb + a10 + k * 64);
            uint4 v3 = *(const uint4*)(xbb + a11 + k * 64);
            uint4 r;
            r.x = hfma2u(v3.x, w11, hfma2u(v2.x, w10, hfma2u(v1.x, w01, hmul2u(v0.x, w00))));
            r.y = hfma2u(v3.y, w11, hfma2u(v2.y, w10, hfma2u(v1.y, w01, hmul2u(v0.y, w00))));
            r.z = hfma2u(v3.z, w11, hfma2u(v2.z, w10, hfma2u(v1.z, w01, hmul2u(v0.z, w00))));
            r.w = hfma2u(v3.w, w11, hfma2u(v2.w, w10, hfma2u(v1.w, w01, hmul2u(v0.w, w00))));
            *(uint4*)&S[buf][pxa][(k << 4) + (lhi << 2)] = r;
        }
        __syncthreads();
        // --- C: MFMA D[o][px] += W_tap * S_tap^T ---
#pragma unroll
        for (int ks = 0; ks < 4; ++ks) {
            U16 sf[4];
#pragma unroll
            for (int pb = 0; pb < 4; ++pb)
                sf[pb].u = *(const uint4*)&S[buf][pb * 16 + l15][(ks * 4 + lhi) << 2];
#pragma unroll
            for (int ob = 0; ob < 2; ++ob) {
                U16 af; af.u = wf[ob][ks];
#pragma unroll
                for (int pb = 0; pb < 4; ++pb)
                    acc[ob][pb] = __builtin_amdgcn_mfma_f32_16x16x32_f16(
                        af.h, sf[pb].h, acc[ob][pb], 0, 0, 0);
            }
        }
    }
    // --- epilogue: o = o0+ob*16+lhi*4+r, px = pb*16+l15 ---
    float* ob_base = out + (size_t)b * 128 * HW_ + ho * 64;
#pragma unroll
    for (int ob = 0; ob < 2; ++ob)
#pragma unroll
        for (int r = 0; r < 4; ++r) {
            int o = o0 + ob * 16 + lhi * 4 + r;
            float bv = bias[o];
#pragma unroll
            for (int pb = 0; pb < 4; ++pb)
                ob_base[(size_t)o * HW_ + pb * 16 + l15] = acc[ob][pb][r] + bv;
        }
}

extern "C" void kernel_launch(void* const* d_in, const int* in_sizes, int n_in,
                              void* d_out, int out_size, void* d_ws, size_t ws_size,
                              hipStream_t stream) {
    const float* x      = (const float*)d_in[0];
    const float* weight = (const float*)d_in[1];
    const float* bias   = (const float*)d_in[2];
    const float* off_w  = (const float*)d_in[3];
    const float* off_b  = (const float*)d_in[4];
    float* out = (float*)d_out;

    u32*   xtu    = (u32*)d_ws;
    float* offout = (float*)(xtu + (size_t)B_ * HW_ * CU_);
    u32*   wtu    = (u32*)(offout + (size_t)B_ * 27 * HW_);
    u32*   woffu  = wtu + 73728;

    hipLaunchKernelGGL(k_transpose, dim3(2048), dim3(256), 0, stream, x, xtu);
    hipLaunchKernelGGL(k_prep, dim3((73728 + 18432 + 255) / 256), dim3(256), 0, stream,
                       weight, off_w, wtu, woffu);
    hipLaunchKernelGGL(k_offconv, dim3(1024), dim3(256), 0, stream, xtu, woffu, off_b, offout);
    hipLaunchKernelGGL(k_fused, dim3(1024), dim3(256), 0, stream, xtu, offout, wtu, bias, out);
}

// Round 7
// 118.281 us; speedup vs baseline: 1.2891x; 1.2891x over previous
//
#include <hip/hip_runtime.h>
#include <hip/hip_fp16.h>

// DCNv2 R7: R5's coalesced broadcast gather + cross-tap software pipeline.
//   Per tap n (k_fused): blend A-half (loads issued last iter), issue B-half,
//   compute params(n+1), blend B, barrier, issue A-half(n+1) loads, MFMA(n).
//   offout prefetched 2 taps ahead; addr readlanes 2/px (a01/a10 via SALU
//   bit-splice); weights packed (w,w) per lane, 4 readlanes/px at blend.
//   S double-buffered [2][64][68]; launch_bounds(256,3) to avoid spill.

typedef unsigned int u32;
typedef __attribute__((ext_vector_type(8))) _Float16 f16x8;
typedef __attribute__((ext_vector_type(4))) float f32x4;

union U16 { uint4 u; f16x8 h; };
union H2U { __half2 h2; u32 u; };

static __device__ __forceinline__ u32 pkh(float a, float b) {
    H2U c; c.h2 = __float22half2_rn(make_float2(a, b)); return c.u;
}
static __device__ __forceinline__ u32 pkw(float w) {
    __half h = __float2half_rn(w);
    H2U c; c.h2 = __half2(h, h); return c.u;
}
static __device__ __forceinline__ u32 hfma2u(u32 a, u32 w, u32 acc) {
    H2U x, y, z; x.u = a; y.u = w; z.u = acc;
    z.h2 = __hfma2(x.h2, y.h2, z.h2); return z.u;
}
static __device__ __forceinline__ u32 hmul2u(u32 a, u32 w) {
    H2U x, y; x.u = a; y.u = w;
    y.h2 = __hmul2(x.h2, y.h2); return y.u;
}

#define B_   16
#define HW_  4096
#define CU_  64          // 128 ch = 64 fp16-pair words

// ---------------- kernel 1: NCHW f32 -> NHWC fp16 ----------------
__global__ __launch_bounds__(256) void k_transpose(const float* __restrict__ x,
                                                   u32* __restrict__ xtu) {
    __shared__ float tile[32][129];
    int blk = blockIdx.x, t = threadIdx.x;
    int b = blk >> 7, hw0 = (blk & 127) << 5;
    int hwl = t & 31, cg = t >> 5;
    const float* src = x + (size_t)b * 128 * HW_ + hw0 + hwl;
#pragma unroll
    for (int i = 0; i < 16; ++i) { int c = cg + (i << 3); tile[hwl][c] = src[(size_t)c * HW_]; }
    __syncthreads();
    u32* dst = xtu + ((size_t)b * HW_ + hw0) * CU_;
    int u = t & 63, hq = t >> 6;
#pragma unroll
    for (int j = 0; j < 8; ++j) {
        int hw = (hq << 3) + j;
        dst[(size_t)hw * CU_ + u] = pkh(tile[hw][2 * u], tile[hw][2 * u + 1]);
    }
}

// ---------------- kernel 2: weight prep ----------------
__global__ __launch_bounds__(256) void k_prep(const float* __restrict__ weight,
                                              const float* __restrict__ off_w,
                                              u32* __restrict__ wtu,
                                              u32* __restrict__ woffu) {
    int idx = blockIdx.x * 256 + threadIdx.x;
    if (idx < 73728) {
        int o = idx / 576, r = idx % 576;
        int n = r / 64, cu = r % 64, c = cu * 2;
        float a = weight[((size_t)(o * 128 + c)) * 9 + n];
        float b = weight[((size_t)(o * 128 + c + 1)) * 9 + n];
        wtu[idx] = pkh(a, b);
    } else if (idx < 73728 + 18432) {
        int k = idx - 73728;
        int o = k / 576, r = k % 576;
        int tap = r / 64, cu = r % 64, c = cu * 2;
        u32 v = 0u;
        if (o < 27) {
            float a = off_w[((size_t)(o * 128 + c)) * 9 + tap];
            float b = off_w[((size_t)(o * 128 + c + 1)) * 9 + tap];
            v = pkh(a, b);
        }
        woffu[k] = v;
    }
}

// ---------------- kernel 3: offset/mask conv via MFMA ----------------
__global__ __launch_bounds__(256) void k_offconv(const u32* __restrict__ xtu,
                                                 const u32* __restrict__ woffu,
                                                 const float* __restrict__ off_b,
                                                 float* __restrict__ offout) {
    __shared__ __align__(16) u32 S[3][64][64];
    int blk = ((blockIdx.x & 7) << 7) + (blockIdx.x >> 3);   // XCD-chunked
    int t = threadIdx.x;
    int b = blk >> 6, ho = blk & 63;
    const u32* xb = xtu + (size_t)b * HW_ * CU_;
    const uint4 z4 = {0u, 0u, 0u, 0u};
#pragma unroll
    for (int i = 0; i < 12; ++i) {
        int li = t + (i << 8);
        int r = li >> 10, rem = li & 1023;
        int px = rem >> 4, ch = rem & 15;
        int yy = ho + r - 1;
        uint4 v = ((unsigned)yy < 64u) ? *(const uint4*)(xb + ((yy << 6) + px) * CU_ + (ch << 2)) : z4;
        *(uint4*)&S[r][px][(ch ^ (px & 7)) << 2] = v;
    }
    __syncthreads();
    int lane = t & 63, w = t >> 6, l15 = lane & 15, lhi = lane >> 4;
    int ob = w >> 1, pb0 = (w & 1) << 1;
    f32x4 acc[2];
    acc[0] = (f32x4){0.f, 0.f, 0.f, 0.f};
    acc[1] = (f32x4){0.f, 0.f, 0.f, 0.f};
#pragma unroll 1
    for (int tap = 0; tap < 9; ++tap) {
        int ky = tap / 3, kx = tap % 3;
        int yy = ho + ky - 1;
        if ((unsigned)yy >= 64u) continue;
        U16 af[4];
#pragma unroll
        for (int ks = 0; ks < 4; ++ks)
            af[ks].u = *(const uint4*)(woffu + (size_t)(ob * 16 + l15) * 576
                                       + tap * 64 + ks * 16 + lhi * 4);
#pragma unroll
        for (int pp = 0; pp < 2; ++pp) {
            int pr = ((pb0 + pp) << 4) + l15;
            int pxs = pr + kx - 1;
            bool v = (unsigned)pxs < 64u;
            int pxc = v ? pxs : 0;
#pragma unroll
            for (int ks = 0; ks < 4; ++ks) {
                U16 sf;
                sf.u = v ? *(const uint4*)&S[ky][pxc][((ks * 4 + lhi) ^ (pxc & 7)) << 2] : z4;
                acc[pp] = __builtin_amdgcn_mfma_f32_16x16x32_f16(af[ks].h, sf.h, acc[pp], 0, 0, 0);
            }
        }
    }
    float* dst = offout + (size_t)b * 27 * HW_ + (ho << 6);
#pragma unroll
    for (int pp = 0; pp < 2; ++pp)
#pragma unroll
        for (int r = 0; r < 4; ++r) {
            int o = ob * 16 + lhi * 4 + r;
            if (o < 27) {
                float s = acc[pp][r] + off_b[o];
                if (o >= 18) s = 1.f / (1.f + __expf(-s));
                dst[(size_t)o * HW_ + ((pb0 + pp) << 4) + l15] = s;
            }
        }
}

// ---------------- kernel 4: fused sample + MFMA, pipelined ----------------
__global__ __launch_bounds__(256, 3) void k_fused(const u32* __restrict__ xtu,
                                                  const float* __restrict__ offout,
                                                  const u32* __restrict__ wtu,
                                                  const float* __restrict__ bias,
                                                  float* __restrict__ out) {
    __shared__ __align__(16) u32 S[2][64][68];   // dbuf, 68-word rows
    int blk = ((blockIdx.x & 7) << 7) + (blockIdx.x >> 3);   // XCD-chunked
    int t = threadIdx.x;
    int b = blk >> 6, ho = blk & 63;
    int w = t >> 6, lane = t & 63, l15 = lane & 15, lhi = lane >> 4;
    int o0 = w * 32;
    int pxa = (w << 4) + l15;        // pixel this lane owns params for

    f32x4 acc[2][4];
#pragma unroll
    for (int ob = 0; ob < 2; ++ob)
#pragma unroll
        for (int pb = 0; pb < 4; ++pb) acc[ob][pb] = (f32x4){0.f, 0.f, 0.f, 0.f};

    const float* offb = offout + (size_t)b * 27 * HW_ + ho * 64 + pxa;
    const u32* xb = xtu + (size_t)b * HW_ * CU_;

    // params: packed (w,w) weights + 2 corner word-addrs; cur / nxt
    u32 cu00, cu01, cu10, cu11, nu00, nu01, nu10, nu11;
    int ca00, ca11, na00, na11;
    float oady, oadx, oam;   // O(n+1) values
    float obdy, obdx, obm;   // O(n+2) in flight

    auto cparams = [&](int n, float dy, float dx, float m,
                       u32& q00, u32& q01, u32& q10, u32& q11, int& r00, int& r11) {
        float ys = (float)(ho + n / 3 - 1) + dy;
        float xs = (float)(pxa + n % 3 - 1) + dx;
        float y0f = floorf(ys), x0f = floorf(xs);
        float fy = ys - y0f, fx = xs - x0f;
        int y0 = (int)y0f, x0 = (int)x0f;
        bool vy0 = (unsigned)y0 < 64u, vy1 = (unsigned)(y0 + 1) < 64u;
        bool vx0 = (unsigned)x0 < 64u, vx1 = (unsigned)(x0 + 1) < 64u;
        q00 = pkw((vy0 && vx0) ? (1.f - fy) * (1.f - fx) * m : 0.f);
        q01 = pkw((vy0 && vx1) ? (1.f - fy) * fx * m : 0.f);
        q10 = pkw((vy1 && vx0) ? fy * (1.f - fx) * m : 0.f);
        q11 = pkw((vy1 && vx1) ? fy * fx * m : 0.f);
        int y0c = min(max(y0, 0), 63), y1c = min(max(y0 + 1, 0), 63);
        int x0c = min(max(x0, 0), 63), x1c = min(max(x0 + 1, 0), 63);
        r00 = (y0c << 12) + (x0c << 6);
        r11 = (y1c << 12) + (x1c << 6);
    };

#define ISSUE8(LD, J0, A00R, A11R)                                          \
    _Pragma("unroll") for (int j = 0; j < 8; ++j) {                         \
        int sa00 = __builtin_amdgcn_readlane(A00R, J0 + j);                 \
        int sa11 = __builtin_amdgcn_readlane(A11R, J0 + j);                 \
        int sa01 = (sa00 & ~0xFFF) | (sa11 & 0xFFF);                        \
        int sa10 = (sa11 & ~0xFFF) | (sa00 & 0xFFF);                        \
        LD[j][0] = xb[sa00 + lane];  LD[j][1] = xb[sa01 + lane];            \
        LD[j][2] = xb[sa10 + lane];  LD[j][3] = xb[sa11 + lane];            \
    }

#define BLEND8(LD, J0, BUF, U00, U01, U10, U11)                             \
    _Pragma("unroll") for (int j = 0; j < 8; ++j) {                         \
        u32 s0 = (u32)__builtin_amdgcn_readlane((int)U00, J0 + j);          \
        u32 s1 = (u32)__builtin_amdgcn_readlane((int)U01, J0 + j);          \
        u32 s2 = (u32)__builtin_amdgcn_readlane((int)U10, J0 + j);          \
        u32 s3 = (u32)__builtin_amdgcn_readlane((int)U11, J0 + j);          \
        u32 r = hfma2u(LD[j][3], s3, hfma2u(LD[j][2], s2,                   \
                hfma2u(LD[j][1], s1, hmul2u(LD[j][0], s0))));               \
        S[BUF][(w << 4) + J0 + j][lane] = r;                                \
    }

    u32 ldA[8][4], ldB[8][4];

    // --- prologue: params(0), O(1) prefetch, issue A-half of tap 0 ---
    {
        float dy = offb[0], dx = offb[(size_t)HW_], m = offb[(size_t)18 * HW_];
        cparams(0, dy, dx, m, cu00, cu01, cu10, cu11, ca00, ca11);
    }
    oady = offb[(size_t)2 * HW_];
    oadx = offb[(size_t)3 * HW_];
    oam  = offb[(size_t)19 * HW_];
    ISSUE8(ldA, 0, ca00, ca11);

#pragma unroll 1
    for (int n = 0; n < 9; ++n) {
        int buf = n & 1;
        BLEND8(ldA, 0, buf, cu00, cu01, cu10, cu11);
        ISSUE8(ldB, 8, ca00, ca11);
        if (n < 8)
            cparams(n + 1, oady, oadx, oam, nu00, nu01, nu10, nu11, na00, na11);
        BLEND8(ldB, 8, buf, cu00, cu01, cu10, cu11);
        if (n < 7) {
            obdy = offb[(size_t)(2 * (n + 2)) * HW_];
            obdx = offb[(size_t)(2 * (n + 2) + 1) * HW_];
            obm  = offb[(size_t)(18 + n + 2) * HW_];
        }
        __syncthreads();
        if (n < 8) { ISSUE8(ldA, 0, na00, na11); }
        // --- MFMA tap n from S[buf] ---
        uint4 wf[2][4];
#pragma unroll
        for (int ob = 0; ob < 2; ++ob)
#pragma unroll
            for (int ks = 0; ks < 4; ++ks)
                wf[ob][ks] = *(const uint4*)(wtu + (size_t)(o0 + ob * 16 + l15) * 576
                                             + n * 64 + ks * 16 + lhi * 4);
#pragma unroll
        for (int ks = 0; ks < 4; ++ks) {
            U16 sf[4];
#pragma unroll
            for (int pb = 0; pb < 4; ++pb)
                sf[pb].u = *(const uint4*)&S[buf][pb * 16 + l15][(ks * 4 + lhi) << 2];
#pragma unroll
            for (int ob = 0; ob < 2; ++ob) {
                U16 af; af.u = wf[ob][ks];
#pragma unroll
                for (int pb = 0; pb < 4; ++pb)
                    acc[ob][pb] = __builtin_amdgcn_mfma_f32_16x16x32_f16(
                        af.h, sf[pb].h, acc[ob][pb], 0, 0, 0);
            }
        }
        // --- rotate pipeline regs ---
        if (n < 8) {
            cu00 = nu00; cu01 = nu01; cu10 = nu10; cu11 = nu11;
            ca00 = na00; ca11 = na11;
            oady = obdy; oadx = obdx; oam = obm;
        }
    }
    // --- epilogue: o = o0+ob*16+lhi*4+r, px = pb*16+l15 ---
    float* ob_base = out + (size_t)b * 128 * HW_ + ho * 64;
#pragma unroll
    for (int ob = 0; ob < 2; ++ob)
#pragma unroll
        for (int r = 0; r < 4; ++r) {
            int o = o0 + ob * 16 + lhi * 4 + r;
            float bv = bias[o];
#pragma unroll
            for (int pb = 0; pb < 4; ++pb)
                ob_base[(size_t)o * HW_ + pb * 16 + l15] = acc[ob][pb][r] + bv;
        }
#undef ISSUE8
#undef BLEND8
}

extern "C" void kernel_launch(void* const* d_in, const int* in_sizes, int n_in,
                              void* d_out, int out_size, void* d_ws, size_t ws_size,
                              hipStream_t stream) {
    const float* x      = (const float*)d_in[0];
    const float* weight = (const float*)d_in[1];
    const float* bias   = (const float*)d_in[2];
    const float* off_w  = (const float*)d_in[3];
    const float* off_b  = (const float*)d_in[4];
    float* out = (float*)d_out;

    u32*   xtu    = (u32*)d_ws;
    float* offout = (float*)(xtu + (size_t)B_ * HW_ * CU_);
    u32*   wtu    = (u32*)(offout + (size_t)B_ * 27 * HW_);
    u32*   woffu  = wtu + 73728;

    hipLaunchKernelGGL(k_transpose, dim3(2048), dim3(256), 0, stream, x, xtu);
    hipLaunchKernelGGL(k_prep, dim3((73728 + 18432 + 255) / 256), dim3(256), 0, stream,
                       weight, off_w, wtu, woffu);
    hipLaunchKernelGGL(k_offconv, dim3(1024), dim3(256), 0, stream, xtu, woffu, off_b, offout);
    hipLaunchKernelGGL(k_fused, dim3(1024), dim3(256), 0, stream, xtu, offout, wtu, bias, out);
}